// Round 1
// baseline (225.523 us; speedup 1.0000x reference)
//
#include <hip/hip_runtime.h>

typedef __attribute__((ext_vector_type(4))) float f32x4;
typedef __attribute__((ext_vector_type(8))) short bf16x8;

__device__ __forceinline__ unsigned short f2b(float f) {
  // round-to-nearest-even f32 -> bf16
  unsigned u = __float_as_uint(f);
  u = (u + 0x7FFFu + ((u >> 16) & 1u)) >> 16;
  return (unsigned short)u;
}

__device__ __forceinline__ void gload_lds16(unsigned short* lds, const unsigned short* g) {
  __builtin_amdgcn_global_load_lds(
      (const __attribute__((address_space(1))) unsigned int*)(g),
      (__attribute__((address_space(3))) unsigned int*)(lds), 16, 0, 0);
}

// ---------------- K1: selector + skill-mix of LoRA params ----------------
// One thread per (b, i), i in [0,2048).
// Art[b][r][i] = sum_t p[b][t] * A[t][i][r]            (bf16, [8][16][2048], k-contig for MFMA B-operand)
// Brt[b][o][r] = (1/16) * sum_t p[b][t] * B[t][r][o]   (bf16, [8][2048][16], r-contig for MFMA B-operand)
__global__ void combine_kernel(const float* __restrict__ logits,   // [32][8]
                               const int*   __restrict__ tasks,    // [8]
                               const float* __restrict__ A,        // [8][2048][16]
                               const float* __restrict__ B,        // [8][16][2048]
                               unsigned short* __restrict__ Art,
                               unsigned short* __restrict__ Brt)
{
  int idx = blockIdx.x * 256 + threadIdx.x;
  int b = idx >> 11;
  int i = idx & 2047;
  if (b >= 8) return;
  int task = tasks[b];
  float p[8]; float s = 0.f;
  #pragma unroll
  for (int t = 0; t < 8; ++t) {
    float l = logits[task * 8 + t];
    float e = 1.f / (1.f + __expf(-l));
    p[t] = e; s += e;
  }
  float inv = 1.f / (s + 1e-12f);
  #pragma unroll
  for (int t = 0; t < 8; ++t) p[t] *= inv;

  float ar[16];
  #pragma unroll
  for (int r = 0; r < 16; ++r) ar[r] = 0.f;
  for (int t = 0; t < 8; ++t) {
    const float* ap = A + ((size_t)t * 2048 + i) * 16;
    float pt = p[t];
    #pragma unroll
    for (int r = 0; r < 16; ++r) ar[r] += pt * ap[r];
  }
  #pragma unroll
  for (int r = 0; r < 16; ++r)
    Art[((size_t)b * 16 + r) * 2048 + i] = f2b(ar[r]);

  float br[16];
  #pragma unroll
  for (int r = 0; r < 16; ++r) br[r] = 0.f;
  for (int t = 0; t < 8; ++t) {
    float pt = p[t];
    #pragma unroll
    for (int r = 0; r < 16; ++r) br[r] += pt * B[((size_t)t * 16 + r) * 2048 + i];
  }
  #pragma unroll
  for (int r = 0; r < 16; ++r)
    Brt[((size_t)b * 2048 + i) * 16 + r] = f2b(br[r] * 0.0625f);
}

// ---------------- K2: W f32 -> bf16 ----------------
__global__ void wconv_kernel(const float* __restrict__ W, unsigned short* __restrict__ Wb) {
  size_t i = ((size_t)blockIdx.x * 256 + threadIdx.x) * 4;
  f32x4 v = *(const f32x4*)(W + i);
  ushort4 o;
  o.x = f2b(v.x); o.y = f2b(v.y); o.z = f2b(v.z); o.w = f2b(v.w);
  *(ushort4*)(Wb + i) = o;
}

// ---------------- K3: x f32 -> bf16, fused xa = x_bf @ A_mix ----------------
// Block: 256 threads (4 waves), 64 rows. Each wave: one 16x16 output frag of xa.
__global__ void xa_conv_kernel(const float* __restrict__ x,            // [16384][2048]
                               const unsigned short* __restrict__ Art, // [8][16][2048]
                               unsigned short* __restrict__ xb,        // [16384][2048]
                               unsigned short* __restrict__ xa)        // [16384][16]
{
  __shared__ unsigned short As[64 * 64];
  int tid = threadIdx.x;
  int lane = tid & 63;
  int wv = tid >> 6;
  int rowbase = blockIdx.x * 64;
  int batch = rowbase >> 11;
  int lr = lane & 15, hi = lane >> 4;
  f32x4 acc; acc.x = 0.f; acc.y = 0.f; acc.z = 0.f; acc.w = 0.f;

  for (int k0 = 0; k0 < 2048; k0 += 64) {
    #pragma unroll
    for (int p = 0; p < 4; ++p) {
      int row = p * 16 + (tid >> 4);
      int k = (tid & 15) * 4;
      f32x4 v = *(const f32x4*)(x + (size_t)(rowbase + row) * 2048 + k0 + k);
      ushort4 o;
      o.x = f2b(v.x); o.y = f2b(v.y); o.z = f2b(v.z); o.w = f2b(v.w);
      *(ushort4*)(xb + (size_t)(rowbase + row) * 2048 + k0 + k) = o;
      *(ushort4*)(As + row * 64 + k) = o;
    }
    __syncthreads();
    #pragma unroll
    for (int kk = 0; kk < 64; kk += 32) {
      bf16x8 a = *(const bf16x8*)(As + (wv * 16 + lr) * 64 + kk + hi * 8);
      bf16x8 bf = *(const bf16x8*)(Art + ((size_t)batch * 16 + lr) * 2048 + k0 + kk + hi * 8);
      acc = __builtin_amdgcn_mfma_f32_16x16x32_bf16(a, bf, acc, 0, 0, 0);
    }
    __syncthreads();
  }
  #pragma unroll
  for (int j = 0; j < 4; ++j) {
    int row = rowbase + wv * 16 + hi * 4 + j;
    xa[(size_t)row * 16 + lr] = f2b(acc[j]);
  }
}

// ---------------- K4: main GEMM (m97 128x128 structure) + fused LoRA/bias epilogue ----------------
__global__ void gemm_kernel(const unsigned short* __restrict__ xb,  // [16384][2048] bf16
                            const unsigned short* __restrict__ Wb,  // [2048][2048]  bf16 (B^T layout)
                            const float* __restrict__ bias,         // [2048]
                            const unsigned short* __restrict__ xa,  // [16384][16]   bf16
                            const unsigned short* __restrict__ Brt, // [8][2048][16] bf16 (pre-scaled 1/16)
                            float* __restrict__ out)                // [16384][2048] f32
{
  __shared__ unsigned short As[128 * 64];
  __shared__ unsigned short Bs[128 * 64];
  int tid = threadIdx.x;
  int lane = tid & 63;
  int wv = tid >> 6;
  int wr = wv >> 1, wc = wv & 1;       // 2x2 waves, each owns 64x64
  int bid = blockIdx.x;
  int tn = bid & 15, tm = bid >> 4;    // consecutive blocks share the M-panel (x reuse in L2)
  int rowbase = tm * 128, colbase = tn * 128;
  int lr = lane & 15, hi = lane >> 4;

  f32x4 acc[4][4];
  #pragma unroll
  for (int m = 0; m < 4; ++m)
    #pragma unroll
    for (int n = 0; n < 4; ++n) { acc[m][n].x = 0.f; acc[m][n].y = 0.f; acc[m][n].z = 0.f; acc[m][n].w = 0.f; }

  for (int k0 = 0; k0 < 2048; k0 += 64) {
    #pragma unroll
    for (int i = 0; i < 4; ++i) {
      int c = tid + i * 256;
      int row = c >> 3, kc = c & 7;
      gload_lds16(As + c * 8, xb + (size_t)(rowbase + row) * 2048 + k0 + kc * 8);
    }
    #pragma unroll
    for (int i = 0; i < 4; ++i) {
      int c = tid + i * 256;
      int row = c >> 3, kc = c & 7;
      gload_lds16(Bs + c * 8, Wb + (size_t)(colbase + row) * 2048 + k0 + kc * 8);
    }
    __syncthreads();
    #pragma unroll
    for (int kk = 0; kk < 64; kk += 32) {
      bf16x8 a[4], bb[4];
      #pragma unroll
      for (int m = 0; m < 4; ++m)
        a[m] = *(const bf16x8*)(As + (wr * 64 + m * 16 + lr) * 64 + kk + hi * 8);
      #pragma unroll
      for (int n = 0; n < 4; ++n)
        bb[n] = *(const bf16x8*)(Bs + (wc * 64 + n * 16 + lr) * 64 + kk + hi * 8);
      #pragma unroll
      for (int m = 0; m < 4; ++m)
        #pragma unroll
        for (int n = 0; n < 4; ++n)
          acc[m][n] = __builtin_amdgcn_mfma_f32_16x16x32_bf16(a[m], bb[n], acc[m][n], 0, 0, 0);
    }
    __syncthreads();
  }

  // --- LoRA epilogue: acc += xa[128x16] @ Brt^T via one zero-padded MFMA per frag ---
  int batch = rowbase >> 11;
  bf16x8 zf = (bf16x8)(short)0;
  bf16x8 av[4], bv[4];
  #pragma unroll
  for (int m = 0; m < 4; ++m) {
    if (hi < 2)
      av[m] = *(const bf16x8*)(xa + (size_t)(rowbase + wr * 64 + m * 16 + lr) * 16 + hi * 8);
    else
      av[m] = zf;
  }
  #pragma unroll
  for (int n = 0; n < 4; ++n) {
    if (hi < 2)
      bv[n] = *(const bf16x8*)(Brt + ((size_t)batch * 2048 + colbase + wc * 64 + n * 16 + lr) * 16 + hi * 8);
    else
      bv[n] = zf;
  }
  #pragma unroll
  for (int m = 0; m < 4; ++m)
    #pragma unroll
    for (int n = 0; n < 4; ++n)
      acc[m][n] = __builtin_amdgcn_mfma_f32_16x16x32_bf16(av[m], bv[n], acc[m][n], 0, 0, 0);

  // --- bias + store (C/D layout: col = lane&15, row = (lane>>4)*4 + j) ---
  #pragma unroll
  for (int n = 0; n < 4; ++n) {
    int col = colbase + wc * 64 + n * 16 + lr;
    float bbv = bias[col];
    #pragma unroll
    for (int m = 0; m < 4; ++m) {
      int row0 = rowbase + wr * 64 + m * 16 + hi * 4;
      #pragma unroll
      for (int j = 0; j < 4; ++j)
        out[(size_t)(row0 + j) * 2048 + col] = acc[m][n][j] + bbv;
    }
  }
}

extern "C" void kernel_launch(void* const* d_in, const int* in_sizes, int n_in,
                              void* d_out, int out_size, void* d_ws, size_t ws_size,
                              hipStream_t stream) {
  const float* x      = (const float*)d_in[0];   // [8][2048][2048]
  const float* W      = (const float*)d_in[1];   // [2048][2048]
  const float* bias   = (const float*)d_in[2];   // [2048]
  const float* logits = (const float*)d_in[3];   // [32][8]
  const float* A      = (const float*)d_in[4];   // [1][8][2048][16]
  const float* B      = (const float*)d_in[5];   // [1][8][16][2048]
  const int*   tasks  = (const int*)d_in[6];     // [8]
  float* out = (float*)d_out;

  char* ws = (char*)d_ws;
  unsigned short* xb  = (unsigned short*)(ws);                         // 67108864 B
  unsigned short* Wb  = (unsigned short*)(ws + 67108864);              //  8388608 B
  unsigned short* xa  = (unsigned short*)(ws + 67108864 + 8388608);    //   524288 B
  unsigned short* Art = (unsigned short*)(ws + 67108864 + 8388608 + 524288);
  unsigned short* Brt = (unsigned short*)(ws + 67108864 + 8388608 + 1048576);

  combine_kernel<<<64, 256, 0, stream>>>(logits, tasks, A, B, Art, Brt);
  wconv_kernel<<<4096, 256, 0, stream>>>(W, Wb);
  xa_conv_kernel<<<256, 256, 0, stream>>>(x, Art, xb, xa);
  gemm_kernel<<<2048, 256, 0, stream>>>(xb, Wb, bias, xa, Brt, out);
}

// Round 2
// 206.456 us; speedup vs baseline: 1.0924x; 1.0924x over previous
//
#include <hip/hip_runtime.h>

typedef __attribute__((ext_vector_type(4))) float f32x4;
typedef __attribute__((ext_vector_type(8))) short bf16x8;

__device__ __forceinline__ unsigned short f2b(float f) {
  unsigned u = __float_as_uint(f);
  u = (u + 0x7FFFu + ((u >> 16) & 1u)) >> 16;
  return (unsigned short)u;
}

#define BAR() asm volatile("s_barrier" ::: "memory")
#define VMCNT(N) asm volatile("s_waitcnt vmcnt(" #N ")" ::: "memory")

// ---------------- K1: selector + skill-mix of LoRA params ----------------
__global__ void combine_kernel(const float* __restrict__ logits,   // [32][8]
                               const int*   __restrict__ tasks,    // [8]
                               const float* __restrict__ A,        // [8][2048][16]
                               const float* __restrict__ B,        // [8][16][2048]
                               unsigned short* __restrict__ Art,   // [8][16][2048]
                               unsigned short* __restrict__ Brt)   // [8][2048][16]
{
  int idx = blockIdx.x * 256 + threadIdx.x;
  int b = idx >> 11;
  int i = idx & 2047;
  if (b >= 8) return;
  int task = tasks[b];
  float p[8]; float s = 0.f;
  #pragma unroll
  for (int t = 0; t < 8; ++t) {
    float l = logits[task * 8 + t];
    float e = 1.f / (1.f + __expf(-l));
    p[t] = e; s += e;
  }
  float inv = 1.f / (s + 1e-12f);
  #pragma unroll
  for (int t = 0; t < 8; ++t) p[t] *= inv;

  float ar[16];
  #pragma unroll
  for (int r = 0; r < 16; ++r) ar[r] = 0.f;
  for (int t = 0; t < 8; ++t) {
    const float* ap = A + ((size_t)t * 2048 + i) * 16;
    float pt = p[t];
    #pragma unroll
    for (int r = 0; r < 16; ++r) ar[r] += pt * ap[r];
  }
  #pragma unroll
  for (int r = 0; r < 16; ++r)
    Art[((size_t)b * 16 + r) * 2048 + i] = f2b(ar[r]);

  float br[16];
  #pragma unroll
  for (int r = 0; r < 16; ++r) br[r] = 0.f;
  for (int t = 0; t < 8; ++t) {
    float pt = p[t];
    #pragma unroll
    for (int r = 0; r < 16; ++r) br[r] += pt * B[((size_t)t * 16 + r) * 2048 + i];
  }
  #pragma unroll
  for (int r = 0; r < 16; ++r)
    Brt[((size_t)b * 2048 + i) * 16 + r] = f2b(br[r] * 0.0625f);
}

// ---------------- K2: W f32 -> bf16 ----------------
__global__ void wconv_kernel(const float* __restrict__ W, unsigned short* __restrict__ Wb) {
  size_t i = ((size_t)blockIdx.x * 256 + threadIdx.x) * 4;
  f32x4 v = *(const f32x4*)(W + i);
  ushort4 o;
  o.x = f2b(v.x); o.y = f2b(v.y); o.z = f2b(v.z); o.w = f2b(v.w);
  *(ushort4*)(Wb + i) = o;
}

// ---------------- K3: x f32 -> bf16, fused xa = x_bf @ A_mix ----------------
__global__ void xa_conv_kernel(const float* __restrict__ x,            // [16384][2048]
                               const unsigned short* __restrict__ Art, // [8][16][2048]
                               unsigned short* __restrict__ xb,        // [16384][2048]
                               unsigned short* __restrict__ xa)        // [16384][16]
{
  __shared__ unsigned short As[64 * 64];
  int tid = threadIdx.x;
  int lane = tid & 63;
  int wv = tid >> 6;
  int rowbase = blockIdx.x * 64;
  int batch = rowbase >> 11;
  int lr = lane & 15, hi = lane >> 4;
  f32x4 acc; acc.x = 0.f; acc.y = 0.f; acc.z = 0.f; acc.w = 0.f;

  for (int k0 = 0; k0 < 2048; k0 += 64) {
    #pragma unroll
    for (int p = 0; p < 4; ++p) {
      int row = p * 16 + (tid >> 4);
      int k = (tid & 15) * 4;
      f32x4 v = *(const f32x4*)(x + (size_t)(rowbase + row) * 2048 + k0 + k);
      ushort4 o;
      o.x = f2b(v.x); o.y = f2b(v.y); o.z = f2b(v.z); o.w = f2b(v.w);
      *(ushort4*)(xb + (size_t)(rowbase + row) * 2048 + k0 + k) = o;
      *(ushort4*)(As + row * 64 + k) = o;
    }
    __syncthreads();
    #pragma unroll
    for (int kk = 0; kk < 64; kk += 32) {
      bf16x8 a = *(const bf16x8*)(As + (wv * 16 + lr) * 64 + kk + hi * 8);
      bf16x8 bf = *(const bf16x8*)(Art + ((size_t)batch * 16 + lr) * 2048 + k0 + kk + hi * 8);
      acc = __builtin_amdgcn_mfma_f32_16x16x32_bf16(a, bf, acc, 0, 0, 0);
    }
    __syncthreads();
  }
  #pragma unroll
  for (int j = 0; j < 4; ++j) {
    int row = rowbase + wv * 16 + hi * 4 + j;
    xa[(size_t)row * 16 + lr] = f2b(acc[j]);
  }
}

// ---------------- K4: 256x256 8-phase GEMM (T2+T3+T4+T5) + LoRA/bias epilogue ----------------
// 512 threads = 8 waves (2 wave-rows x 4 wave-cols). Per-wave output 128x64.
// LDS 128 KiB: buf d at d*65536; A tile [0,32768), B tile [32768,65536).
// Strip-permuted rows so each quadrant-half is a contiguous 16 KiB region:
//   A lds-row = mh*128 + wr*64 + q   (global A row = wr*128 + mh*64 + q)
//   B lds-row = nh*128 + wc*32 + q   (global B row = wc*64  + nh*32 + q)
// XOR swizzle (T2): phys_colbyte = colbyte ^ ((row&7)<<4); inverse applied on global source.
// K-tile kt computed from buf[kt&1]; staged: A1/B1(kt+1) in ph1/ph2, A0/B0(kt+2) in ph3/ph4.
// Counted waits (T4): vmcnt(3) at ph1-end, vmcnt(4) at ph4-end; never 0 in steady state.
__global__ __launch_bounds__(512, 2)
void gemm_kernel(const unsigned short* __restrict__ xb,  // [16384][2048] bf16
                 const unsigned short* __restrict__ Wb,  // [2048][2048]  bf16 (row = out col)
                 const float* __restrict__ bias,         // [2048]
                 const unsigned short* __restrict__ xa,  // [16384][16]   bf16
                 const unsigned short* __restrict__ Brt, // [8][2048][16] bf16 (pre-scaled 1/16)
                 float* __restrict__ out)                // [16384][2048] f32
{
  __shared__ __align__(16) char lds[131072];
  const int tid = threadIdx.x;
  const int lane = tid & 63;
  const int wv = tid >> 6;
  const int wr = wv >> 2, wc = wv & 3;
  const int lr = lane & 15, hi = lane >> 4;
  const int hi16 = hi * 16;

  // XCD-aware swizzle: 512 blocks, 512%8==0 -> each XCD gets 8 contiguous tm panels
  const int bid = blockIdx.x;
  const int swz = (bid & 7) * 64 + (bid >> 3);
  const int tm = swz >> 3, tn = swz & 7;
  const int rowbase = tm * 256, colbase = tn * 256;

  // per-thread staging geometry: chunk row0 = tid>>3, colbyte cb0 = (tid&7)*16
  const int row0 = tid >> 3;
  const int cb0 = (tid & 7) * 16;
  const int scb_e = (cb0 ^ ((row0 & 7) << 4)) >> 1;  // inverse-swizzled source col (elements)
  const int rb5 = ((row0 >> 5) << 6) + (row0 & 31);  // B strip-permute source row piece

#define GL16(LDSOFF, GPTR) \
  __builtin_amdgcn_global_load_lds((const __attribute__((address_space(1))) unsigned int*)(GPTR), \
      (__attribute__((address_space(3))) unsigned int*)(lds + (LDSOFF)), 16, 0, 0)

#define STAGE_A(MH, DBUF, KOFF) { \
  const unsigned short* g_ = xb + (size_t)(rowbase + (MH)*64 + row0) * 2048 + (KOFF) + scb_e; \
  GL16((DBUF)*65536 + (MH)*16384 + tid*16, g_); \
  GL16((DBUF)*65536 + (MH)*16384 + 8192 + tid*16, g_ + 128*2048); \
}
#define STAGE_B(NH, DBUF, KOFF) { \
  const unsigned short* g_ = Wb + (size_t)(colbase + (NH)*32 + rb5) * 2048 + (KOFF) + scb_e; \
  GL16((DBUF)*65536 + 32768 + (NH)*16384 + tid*16, g_); \
  GL16((DBUF)*65536 + 32768 + (NH)*16384 + 8192 + tid*16, g_ + 128*2048); \
}

#define READ_A(MH) \
  _Pragma("unroll") \
  for (int mf = 0; mf < 4; ++mf) { \
    int ar_ = (MH)*128 + wr*64 + mf*16 + lr; \
    _Pragma("unroll") \
    for (int kk = 0; kk < 2; ++kk) \
      a[mf][kk] = *(const bf16x8*)(Ab + ar_*128 + ((kk*64 + hi16) ^ ((ar_&7)<<4))); \
  }
#define READ_B(NH, BREG) \
  _Pragma("unroll") \
  for (int nf = 0; nf < 2; ++nf) { \
    int br_ = (NH)*128 + wc*32 + nf*16 + lr; \
    _Pragma("unroll") \
    for (int kk = 0; kk < 2; ++kk) \
      BREG[nf][kk] = *(const bf16x8*)(Bb + br_*128 + ((kk*64 + hi16) ^ ((br_&7)<<4))); \
  }
#define MFMA_BLOCK(MH, NH, BREG) \
  __builtin_amdgcn_s_setprio(1); \
  _Pragma("unroll") \
  for (int mf = 0; mf < 4; ++mf) \
    _Pragma("unroll") \
    for (int nf = 0; nf < 2; ++nf) \
      _Pragma("unroll") \
      for (int kk = 0; kk < 2; ++kk) \
        acc[(MH)*4+mf][(NH)*2+nf] = __builtin_amdgcn_mfma_f32_16x16x32_bf16( \
            a[mf][kk], BREG[nf][kk], acc[(MH)*4+mf][(NH)*2+nf], 0, 0, 0); \
  __builtin_amdgcn_s_setprio(0);

  f32x4 acc[8][4];
  #pragma unroll
  for (int i = 0; i < 8; ++i)
    #pragma unroll
    for (int n = 0; n < 4; ++n) { acc[i][n].x = 0.f; acc[i][n].y = 0.f; acc[i][n].z = 0.f; acc[i][n].w = 0.f; }

  bf16x8 a[4][2], b0[2][2], b1[2][2];

  // Prologue: kt0 fully + A0/B0(kt1); keep last 4 (A1(0),B1(0),A0(1),B0(1)) in flight
  STAGE_A(0, 0, 0);
  STAGE_B(0, 0, 0);
  STAGE_A(1, 0, 0);
  STAGE_B(1, 0, 0);
  STAGE_A(0, 1, 64);
  STAGE_B(0, 1, 64);
  VMCNT(4);
  BAR();

  for (int kt = 0; kt < 32; ++kt) {
    const int buf = kt & 1, nbuf = buf ^ 1;
    const char* Ab = lds + buf * 65536;
    const char* Bb = Ab + 32768;
    const int k1 = (kt + 1) * 64, k2 = (kt + 2) * 64;

    // ---- ph1: Q(0,0). reads A-mh0 (last use of A0 region), B-nh0; stage A1(kt+1)
    READ_A(0);
    READ_B(0, b0);
    if (kt < 31) STAGE_A(1, nbuf, k1);
    BAR();
    MFMA_BLOCK(0, 0, b0);
    if (kt < 31) { VMCNT(3); } else { VMCNT(0); }   // lands A1(kt),B1(kt) before ph2/ph3 reads
    BAR();

    // ---- ph2: Q(0,1). reads B-nh1; stage B1(kt+1)
    READ_B(1, b1);
    if (kt < 31) STAGE_B(1, nbuf, k1);
    BAR();
    MFMA_BLOCK(0, 1, b1);
    BAR();

    // ---- ph3: Q(1,0). reads A-mh1; stage A0(kt+2) (A0 region free since ph1)
    READ_A(1);
    if (kt < 30) STAGE_A(0, buf, k2);
    BAR();
    MFMA_BLOCK(1, 0, b0);
    BAR();

    // ---- ph4: Q(1,1). no reads; stage B0(kt+2)
    if (kt < 30) STAGE_B(0, buf, k2);
    BAR();
    MFMA_BLOCK(1, 1, b1);
    if (kt < 30) { VMCNT(4); }                      // lands A0,B0(kt+1) before ph1 reads
    else if (kt == 30) { VMCNT(2); }
    BAR();
  }

  // ---- LoRA epilogue: acc += xa[256x16] @ Brt^T via zero-padded MFMA per frag ----
  const int batch = rowbase >> 11;
  bf16x8 zf = (bf16x8)(short)0;
  bf16x8 av[8], bv[4];
  #pragma unroll
  for (int i = 0; i < 8; ++i) {
    if (hi < 2)
      av[i] = *(const bf16x8*)(xa + (size_t)(rowbase + wr * 128 + i * 16 + lr) * 16 + hi * 8);
    else
      av[i] = zf;
  }
  #pragma unroll
  for (int n = 0; n < 4; ++n) {
    if (hi < 2)
      bv[n] = *(const bf16x8*)(Brt + ((size_t)batch * 2048 + colbase + wc * 64 + n * 16 + lr) * 16 + hi * 8);
    else
      bv[n] = zf;
  }
  #pragma unroll
  for (int i = 0; i < 8; ++i)
    #pragma unroll
    for (int n = 0; n < 4; ++n)
      acc[i][n] = __builtin_amdgcn_mfma_f32_16x16x32_bf16(av[i], bv[n], acc[i][n], 0, 0, 0);

  // ---- bias + store (C/D: col = lane&15, row = (lane>>4)*4 + j) ----
  #pragma unroll
  for (int n = 0; n < 4; ++n) {
    int col = colbase + wc * 64 + n * 16 + lr;
    float bbv = bias[col];
    #pragma unroll
    for (int i = 0; i < 8; ++i) {
      int r0 = rowbase + wr * 128 + i * 16 + hi * 4;
      #pragma unroll
      for (int j = 0; j < 4; ++j)
        out[(size_t)(r0 + j) * 2048 + col] = acc[i][n][j] + bbv;
    }
  }
#undef GL16
#undef STAGE_A
#undef STAGE_B
#undef READ_A
#undef READ_B
#undef MFMA_BLOCK
}

extern "C" void kernel_launch(void* const* d_in, const int* in_sizes, int n_in,
                              void* d_out, int out_size, void* d_ws, size_t ws_size,
                              hipStream_t stream) {
  const float* x      = (const float*)d_in[0];   // [8][2048][2048]
  const float* W      = (const float*)d_in[1];   // [2048][2048]
  const float* bias   = (const float*)d_in[2];   // [2048]
  const float* logits = (const float*)d_in[3];   // [32][8]
  const float* A      = (const float*)d_in[4];   // [1][8][2048][16]
  const float* B      = (const float*)d_in[5];   // [1][8][16][2048]
  const int*   tasks  = (const int*)d_in[6];     // [8]
  float* out = (float*)d_out;

  char* ws = (char*)d_ws;
  unsigned short* xb  = (unsigned short*)(ws);                         // 67108864 B
  unsigned short* Wb  = (unsigned short*)(ws + 67108864);              //  8388608 B
  unsigned short* xa  = (unsigned short*)(ws + 67108864 + 8388608);    //   524288 B
  unsigned short* Art = (unsigned short*)(ws + 67108864 + 8388608 + 524288);
  unsigned short* Brt = (unsigned short*)(ws + 67108864 + 8388608 + 1048576);

  combine_kernel<<<64, 256, 0, stream>>>(logits, tasks, A, B, Art, Brt);
  wconv_kernel<<<4096, 256, 0, stream>>>(W, Wb);
  xa_conv_kernel<<<256, 256, 0, stream>>>(x, Art, xb, xa);
  gemm_kernel<<<512, 512, 0, stream>>>(xb, Wb, bias, xa, Brt, out);
}

// Round 3
// 193.262 us; speedup vs baseline: 1.1669x; 1.0683x over previous
//
#include <hip/hip_runtime.h>

typedef __attribute__((ext_vector_type(4))) float f32x4;
typedef __attribute__((ext_vector_type(8))) short bf16x8;

__device__ __forceinline__ unsigned short f2b(float f) {
  unsigned u = __float_as_uint(f);
  u = (u + 0x7FFFu + ((u >> 16) & 1u)) >> 16;
  return (unsigned short)u;
}

#define BAR() asm volatile("s_barrier" ::: "memory")
#define VMCNT(N) asm volatile("s_waitcnt vmcnt(" #N ")" ::: "memory")

// ---------------- K1: selector + skill-mix of LoRA params ----------------
__global__ void combine_kernel(const float* __restrict__ logits,   // [32][8]
                               const int*   __restrict__ tasks,    // [8]
                               const float* __restrict__ A,        // [8][2048][16]
                               const float* __restrict__ B,        // [8][16][2048]
                               unsigned short* __restrict__ Art,   // [8][16][2048]
                               unsigned short* __restrict__ Brt)   // [8][2048][16]
{
  int idx = blockIdx.x * 256 + threadIdx.x;
  int b = idx >> 11;
  int i = idx & 2047;
  if (b >= 8) return;
  int task = tasks[b];
  float p[8]; float s = 0.f;
  #pragma unroll
  for (int t = 0; t < 8; ++t) {
    float l = logits[task * 8 + t];
    float e = 1.f / (1.f + __expf(-l));
    p[t] = e; s += e;
  }
  float inv = 1.f / (s + 1e-12f);
  #pragma unroll
  for (int t = 0; t < 8; ++t) p[t] *= inv;

  float ar[16];
  #pragma unroll
  for (int r = 0; r < 16; ++r) ar[r] = 0.f;
  for (int t = 0; t < 8; ++t) {
    const float* ap = A + ((size_t)t * 2048 + i) * 16;
    float pt = p[t];
    #pragma unroll
    for (int r = 0; r < 16; ++r) ar[r] += pt * ap[r];
  }
  #pragma unroll
  for (int r = 0; r < 16; ++r)
    Art[((size_t)b * 16 + r) * 2048 + i] = f2b(ar[r]);

  float br[16];
  #pragma unroll
  for (int r = 0; r < 16; ++r) br[r] = 0.f;
  for (int t = 0; t < 8; ++t) {
    float pt = p[t];
    #pragma unroll
    for (int r = 0; r < 16; ++r) br[r] += pt * B[((size_t)t * 16 + r) * 2048 + i];
  }
  #pragma unroll
  for (int r = 0; r < 16; ++r)
    Brt[((size_t)b * 2048 + i) * 16 + r] = f2b(br[r] * 0.0625f);
}

// ---------------- K2: prep = {x f32->bf16 + xa = x@A_mix} ∪ {W f32->bf16} ----------------
// Blocks [0,1024): 16 rows each, 4 waves; wave wv owns K-quarter [wv*512, wv*512+512).
//   Per step: load 2x f32x4 of x, convert in regs (A-frag layout: lane=row, hi=k-chunk),
//   write xb, MFMA against Art B-frag. Cross-wave reduce of the 16x16 partial in LDS.
// Blocks [1024,1152): grid-stride W f32->bf16 (32 f32x4 chunks/thread).
__global__ void prep_kernel(const float* __restrict__ x,            // [16384][2048]
                            const unsigned short* __restrict__ Art, // [8][16][2048]
                            const float* __restrict__ W,            // [2048][2048]
                            unsigned short* __restrict__ Wb,        // [2048][2048]
                            unsigned short* __restrict__ xb,        // [16384][2048]
                            unsigned short* __restrict__ xa)        // [16384][16]
{
  __shared__ float red[4][16][16];
  int blk = blockIdx.x;
  int tid = threadIdx.x;
  if (blk >= 1024) {
    int idx0 = (blk - 1024) * 256 + tid;
    #pragma unroll
    for (int c = 0; c < 32; ++c) {
      size_t i = ((size_t)idx0 + (size_t)c * 32768) * 4;
      f32x4 v = *(const f32x4*)(W + i);
      ushort4 o;
      o.x = f2b(v.x); o.y = f2b(v.y); o.z = f2b(v.z); o.w = f2b(v.w);
      *(ushort4*)(Wb + i) = o;
    }
    return;
  }
  int lane = tid & 63, wv = tid >> 6;
  int lr = lane & 15, hi = lane >> 4;
  int rowbase = blk * 16;
  int batch = rowbase >> 11;
  int row = rowbase + lr;
  f32x4 acc; acc.x = 0.f; acc.y = 0.f; acc.z = 0.f; acc.w = 0.f;
  const float* xrow = x + (size_t)row * 2048 + wv * 512 + hi * 8;
  unsigned short* xbrow = xb + (size_t)row * 2048 + wv * 512 + hi * 8;
  const unsigned short* artrow = Art + ((size_t)batch * 16 + lr) * 2048 + wv * 512 + hi * 8;
  #pragma unroll
  for (int ks = 0; ks < 16; ++ks) {
    f32x4 v0 = *(const f32x4*)(xrow + ks * 32);
    f32x4 v1 = *(const f32x4*)(xrow + ks * 32 + 4);
    bf16x8 av;
    av[0] = (short)f2b(v0.x); av[1] = (short)f2b(v0.y);
    av[2] = (short)f2b(v0.z); av[3] = (short)f2b(v0.w);
    av[4] = (short)f2b(v1.x); av[5] = (short)f2b(v1.y);
    av[6] = (short)f2b(v1.z); av[7] = (short)f2b(v1.w);
    *(bf16x8*)(xbrow + ks * 32) = av;
    bf16x8 bv = *(const bf16x8*)(artrow + ks * 32);
    acc = __builtin_amdgcn_mfma_f32_16x16x32_bf16(av, bv, acc, 0, 0, 0);
  }
  #pragma unroll
  for (int j = 0; j < 4; ++j) red[wv][hi * 4 + j][lr] = acc[j];
  __syncthreads();
  int rr = tid >> 4, cc = tid & 15;
  float s = red[0][rr][cc] + red[1][rr][cc] + red[2][rr][cc] + red[3][rr][cc];
  xa[(size_t)(rowbase + rr) * 16 + cc] = f2b(s);
}

// ---------------- K3: 256x256 8-phase GEMM (T2+T3+T4+T5) + LoRA/bias epilogue ----------------
// 512 threads = 8 waves (2 x 4). Per-wave output 128x64. LDS 128 KiB, 2 bufs.
// Strip-permuted LDS rows (linear gload_lds dests); T2 XOR swizzle both-sides.
//
// vmcnt LEDGER (FIFO, 2 loads per half-tile). Issues: ph1:A1(kt+1) ph2:B1(kt+1)
// ph3:A0(kt+2) ph4:B0(kt+2). Reads: ph1:A0(kt),B0(kt); ph2:B1(kt); ph3:A1(kt).
// Steady state at ph4-end after VMCNT(6): queue=[B1(kt+1),A0(kt+2),B0(kt+2)].
//   ph1-end VMCNT(6): queue 8->6, lands B1(kt)     (3 phases of flight) -> ph2 safe
//   ph4-end VMCNT(6): queue 12->6, lands A0,B0,A1(kt+1) (3-5 phases)    -> next ph1/ph3 safe
// Tail: kt==30 ph4 VMCNT(4) (lands A0,B0(31)); kt==31 ph1 VMCNT(0).
// Prologue: 12 loads, VMCNT(8) lands A0(0),B0(0).
__global__ __launch_bounds__(512, 2)
void gemm_kernel(const unsigned short* __restrict__ xb,  // [16384][2048] bf16
                 const unsigned short* __restrict__ Wb,  // [2048][2048]  bf16 (row = out col)
                 const float* __restrict__ bias,         // [2048]
                 const unsigned short* __restrict__ xa,  // [16384][16]   bf16
                 const unsigned short* __restrict__ Brt, // [8][2048][16] bf16 (pre-scaled 1/16)
                 float* __restrict__ out)                // [16384][2048] f32
{
  __shared__ __align__(16) char lds[131072];
  const int tid = threadIdx.x;
  const int lane = tid & 63;
  const int wv = tid >> 6;
  const int wr = wv >> 2, wc = wv & 3;
  const int lr = lane & 15, hi = lane >> 4;
  const int hi16 = hi * 16;

  const int bid = blockIdx.x;
  const int swz = (bid & 7) * 64 + (bid >> 3);
  const int tm = swz >> 3, tn = swz & 7;
  const int rowbase = tm * 256, colbase = tn * 256;

  const int row0 = tid >> 3;
  const int cb0 = (tid & 7) * 16;
  const int scb_e = (cb0 ^ ((row0 & 7) << 4)) >> 1;
  const int rb5 = ((row0 >> 5) << 6) + (row0 & 31);

#define GL16(LDSOFF, GPTR) \
  __builtin_amdgcn_global_load_lds((const __attribute__((address_space(1))) unsigned int*)(GPTR), \
      (__attribute__((address_space(3))) unsigned int*)(lds + (LDSOFF)), 16, 0, 0)

#define STAGE_A(MH, DBUF, KOFF) { \
  const unsigned short* g_ = xb + (size_t)(rowbase + (MH)*64 + row0) * 2048 + (KOFF) + scb_e; \
  GL16((DBUF)*65536 + (MH)*16384 + tid*16, g_); \
  GL16((DBUF)*65536 + (MH)*16384 + 8192 + tid*16, g_ + 128*2048); \
}
#define STAGE_B(NH, DBUF, KOFF) { \
  const unsigned short* g_ = Wb + (size_t)(colbase + (NH)*32 + rb5) * 2048 + (KOFF) + scb_e; \
  GL16((DBUF)*65536 + 32768 + (NH)*16384 + tid*16, g_); \
  GL16((DBUF)*65536 + 32768 + (NH)*16384 + 8192 + tid*16, g_ + 128*2048); \
}

#define READ_A(MH) \
  _Pragma("unroll") \
  for (int mf = 0; mf < 4; ++mf) { \
    int ar_ = (MH)*128 + wr*64 + mf*16 + lr; \
    _Pragma("unroll") \
    for (int kk = 0; kk < 2; ++kk) \
      a[mf][kk] = *(const bf16x8*)(Ab + ar_*128 + ((kk*64 + hi16) ^ ((ar_&7)<<4))); \
  }
#define READ_B(NH, BREG) \
  _Pragma("unroll") \
  for (int nf = 0; nf < 2; ++nf) { \
    int br_ = (NH)*128 + wc*32 + nf*16 + lr; \
    _Pragma("unroll") \
    for (int kk = 0; kk < 2; ++kk) \
      BREG[nf][kk] = *(const bf16x8*)(Bb + br_*128 + ((kk*64 + hi16) ^ ((br_&7)<<4))); \
  }
#define MFMA_BLOCK(MH, NH, BREG) \
  __builtin_amdgcn_s_setprio(1); \
  _Pragma("unroll") \
  for (int mf = 0; mf < 4; ++mf) \
    _Pragma("unroll") \
    for (int nf = 0; nf < 2; ++nf) \
      _Pragma("unroll") \
      for (int kk = 0; kk < 2; ++kk) \
        acc[(MH)*4+mf][(NH)*2+nf] = __builtin_amdgcn_mfma_f32_16x16x32_bf16( \
            a[mf][kk], BREG[nf][kk], acc[(MH)*4+mf][(NH)*2+nf], 0, 0, 0); \
  __builtin_amdgcn_s_setprio(0);

  f32x4 acc[8][4];
  #pragma unroll
  for (int i = 0; i < 8; ++i)
    #pragma unroll
    for (int n = 0; n < 4; ++n) { acc[i][n].x = 0.f; acc[i][n].y = 0.f; acc[i][n].z = 0.f; acc[i][n].w = 0.f; }

  bf16x8 a[4][2], b0[2][2], b1[2][2];

  // Prologue: kt0 fully + A0/B0(kt1). VMCNT(8) lands A0(0),B0(0).
  STAGE_A(0, 0, 0);
  STAGE_B(0, 0, 0);
  STAGE_A(1, 0, 0);
  STAGE_B(1, 0, 0);
  STAGE_A(0, 1, 64);
  STAGE_B(0, 1, 64);
  VMCNT(8);
  BAR();

  for (int kt = 0; kt < 32; ++kt) {
    const int buf = kt & 1, nbuf = buf ^ 1;
    const char* Ab = lds + buf * 65536;
    const char* Bb = Ab + 32768;
    const int k1 = (kt + 1) * 64, k2 = (kt + 2) * 64;

    // ---- ph1: Q(0,0); stage A1(kt+1)
    READ_A(0);
    READ_B(0, b0);
    if (kt < 31) STAGE_A(1, nbuf, k1);
    BAR();
    MFMA_BLOCK(0, 0, b0);
    if (kt < 31) { VMCNT(6); } else { VMCNT(0); }
    BAR();

    // ---- ph2: Q(0,1); stage B1(kt+1)
    READ_B(1, b1);
    if (kt < 31) STAGE_B(1, nbuf, k1);
    BAR();
    MFMA_BLOCK(0, 1, b1);
    BAR();

    // ---- ph3: Q(1,0); stage A0(kt+2)
    READ_A(1);
    if (kt < 30) STAGE_A(0, buf, k2);
    BAR();
    MFMA_BLOCK(1, 0, b0);
    BAR();

    // ---- ph4: Q(1,1); stage B0(kt+2)
    if (kt < 30) STAGE_B(0, buf, k2);
    BAR();
    MFMA_BLOCK(1, 1, b1);
    if (kt < 30) { VMCNT(6); }
    else if (kt == 30) { VMCNT(4); }
    BAR();
  }

  // ---- LoRA epilogue: acc += xa[256x16] @ Brt^T via zero-padded MFMA per frag ----
  const int batch = rowbase >> 11;
  bf16x8 zf = (bf16x8)(short)0;
  bf16x8 av[8], bv[4];
  #pragma unroll
  for (int i = 0; i < 8; ++i) {
    if (hi < 2)
      av[i] = *(const bf16x8*)(xa + (size_t)(rowbase + wr * 128 + i * 16 + lr) * 16 + hi * 8);
    else
      av[i] = zf;
  }
  #pragma unroll
  for (int n = 0; n < 4; ++n) {
    if (hi < 2)
      bv[n] = *(const bf16x8*)(Brt + ((size_t)batch * 2048 + colbase + wc * 64 + n * 16 + lr) * 16 + hi * 8);
    else
      bv[n] = zf;
  }
  #pragma unroll
  for (int i = 0; i < 8; ++i)
    #pragma unroll
    for (int n = 0; n < 4; ++n)
      acc[i][n] = __builtin_amdgcn_mfma_f32_16x16x32_bf16(av[i], bv[n], acc[i][n], 0, 0, 0);

  // ---- bias + store (C/D: col = lane&15, row = (lane>>4)*4 + j) ----
  #pragma unroll
  for (int n = 0; n < 4; ++n) {
    int col = colbase + wc * 64 + n * 16 + lr;
    float bbv = bias[col];
    #pragma unroll
    for (int i = 0; i < 8; ++i) {
      int r0 = rowbase + wr * 128 + i * 16 + hi * 4;
      #pragma unroll
      for (int j = 0; j < 4; ++j)
        out[(size_t)(r0 + j) * 2048 + col] = acc[i][n][j] + bbv;
    }
  }
#undef GL16
#undef STAGE_A
#undef STAGE_B
#undef READ_A
#undef READ_B
#undef MFMA_BLOCK
}

extern "C" void kernel_launch(void* const* d_in, const int* in_sizes, int n_in,
                              void* d_out, int out_size, void* d_ws, size_t ws_size,
                              hipStream_t stream) {
  const float* x      = (const float*)d_in[0];   // [8][2048][2048]
  const float* W      = (const float*)d_in[1];   // [2048][2048]
  const float* bias   = (const float*)d_in[2];   // [2048]
  const float* logits = (const float*)d_in[3];   // [32][8]
  const float* A      = (const float*)d_in[4];   // [1][8][2048][16]
  const float* B      = (const float*)d_in[5];   // [1][8][16][2048]
  const int*   tasks  = (const int*)d_in[6];     // [8]
  float* out = (float*)d_out;

  char* ws = (char*)d_ws;
  unsigned short* xb  = (unsigned short*)(ws);                         // 67108864 B
  unsigned short* Wb  = (unsigned short*)(ws + 67108864);              //  8388608 B
  unsigned short* xa  = (unsigned short*)(ws + 67108864 + 8388608);    //   524288 B
  unsigned short* Art = (unsigned short*)(ws + 67108864 + 8388608 + 524288);
  unsigned short* Brt = (unsigned short*)(ws + 67108864 + 8388608 + 1048576);

  combine_kernel<<<64, 256, 0, stream>>>(logits, tasks, A, B, Art, Brt);
  prep_kernel<<<1152, 256, 0, stream>>>(x, Art, W, Wb, xb, xa);
  gemm_kernel<<<512, 512, 0, stream>>>(xb, Wb, bias, xa, Brt, out);
}